// Round 2
// baseline (434.031 us; speedup 1.0000x reference)
//
#include <hip/hip_runtime.h>
#include <hip/hip_fp16.h>

// Problem constants
#define B_ 64
#define H_ 256
#define W_ 256
#define SW_ 132              // stored width: k2 in [0,128] real, [129,131] zero pad
#define SIMG_ (H_ * SW_)     // 33792 half2 per channel plane
#define TIMG_ (3 * SIMG_)    // 101376 half2 per batch item per tensor
#define NCH_ (B_ * 3)        // 192 channel planes per tensor
#define NROWS_ (B_ * 3 * H_) // 49152 rows per tensor
#define TELEMS_ ((size_t)B_ * TIMG_)  // 6488064 half2 per tensor

// -------- Stockham radix-2 256-pt FFT in LDS (one 64-lane wave per transform)
// Result ends in the buffer originally passed as sp after 8 stages.
__device__ __forceinline__ void fft256(float2* sp, float2* dp, int r) {
  int l = 128;
#pragma unroll
  for (int s = 0; s < 8; ++s) {
#pragma unroll
    for (int t = 0; t < 2; ++t) {
      int idx = r + t * 64;
      int m = 1 << s;
      int j = idx >> s;
      float2 c0 = sp[idx];
      float2 c1 = sp[idx + 128];
      float ang = -3.14159265358979323846f * (float)j / (float)l;
      float sw, cw;
      __sincosf(ang, &sw, &cw);
      float2 d0 = make_float2(c0.x + c1.x, c0.y + c1.y);
      float ex = c0.x - c1.x, ey = c0.y - c1.y;
      float2 d1 = make_float2(ex * cw - ey * sw, ex * sw + ey * cw);
      int dst0 = idx + j * m;  // = k + 2*j*m
      dp[dst0] = d0;
      dp[dst0 + m] = d1;
    }
    l >>= 1;
    float2* tmp = sp; sp = dp; dp = tmp;
    __syncthreads();
  }
}

// -------- Row FFT: real input -> half2 spectrum, cols [0,128] kept ---------
__global__ __launch_bounds__(256) void fft_rows(const float* __restrict__ in,
                                                __half2* __restrict__ out) {
  __shared__ float2 bufA[4][256];
  __shared__ float2 bufB[4][256];
  int rib = threadIdx.x >> 6;   // row in block 0..3
  int r = threadIdx.x & 63;
  int row = blockIdx.x * 4 + rib;
  const float* src = in + (size_t)row * 256;
  float2* sA = bufA[rib];
  float2* sB = bufB[rib];
#pragma unroll
  for (int t = 0; t < 4; ++t) {
    int h = r + t * 64;
    sA[h] = make_float2(src[h], 0.0f);
  }
  __syncthreads();
  fft256(sA, sB, r);
  __half2* op = out + (size_t)row * SW_;
  op[r] = __floats2half2_rn(sA[r].x, sA[r].y);
  op[64 + r] = __floats2half2_rn(sA[64 + r].x, sA[64 + r].y);
  if (r < 4) {
    float2 v = (r == 0) ? sA[128] : make_float2(0.0f, 0.0f);
    op[128 + r] = __floats2half2_rn(v.x, v.y);
  }
}

// -------- Column FFT, in place on half2, 4 columns per block ---------------
__global__ __launch_bounds__(256) void fft_cols(__half2* __restrict__ data) {
  __shared__ float2 bufA[4][256];
  __shared__ float2 bufB[4][256];
  int img = blockIdx.y;           // 0..191
  int w0 = blockIdx.x * 4;        // 0..128 step 4 (33 groups)
  __half2* base = data + (size_t)img * SIMG_;
#pragma unroll
  for (int t = 0; t < 4; ++t) {
    int flat = threadIdx.x + t * 256;
    int h = flat >> 2;
    int wc = flat & 3;
    bufA[wc][h] = __half22float2(base[h * SW_ + w0 + wc]);
  }
  __syncthreads();
  int col = threadIdx.x >> 6;     // one wave per column
  int r = threadIdx.x & 63;
  fft256(bufA[col], bufB[col], r);
#pragma unroll
  for (int t = 0; t < 4; ++t) {
    int flat = threadIdx.x + t * 256;
    int h = flat >> 2;
    int wc = flat & 3;
    base[h * SW_ + w0 + wc] = __float22half2_rn(bufA[wc][h]);
  }
}

__device__ __forceinline__ float cab2(float2 v) { return v.x * v.x + v.y * v.y; }

// -------- Fused normalize + triplet distance accumulation ------------------
// Half-grid sum with Hermitian weights: w=1 for k2 in {0,128}, w=2 for [1,127].
// Padded cols 129..131 hold zeros -> contribute exactly 0.
__global__ __launch_bounds__(256) void dist_kernel(const __half2* __restrict__ af,
                                                   const __half2* __restrict__ pf,
                                                   const __half2* __restrict__ nf,
                                                   const int* __restrict__ neg,
                                                   float* __restrict__ acc) {
  int b = blockIdx.y;
  // neg_idx layout autodetect: int64 little-endian -> word[1] (hi of elem 0) == 0;
  // int32 -> word[1] = j0 which is never 0 (offset in [1,B)).
  int j;
  if (neg[1] == 0) {
    j = (int)((const long long*)neg)[b * 2 + 1];
  } else {
    j = neg[b * 2 + 1];
  }
  size_t ab = (size_t)b * TIMG_;
  size_t jb = (size_t)j * TIMG_;
  float s_ap = 0.0f, s_a0 = 0.0f, s_a1 = 0.0f;
#pragma unroll
  for (int t = 0; t < 4; ++t) {
    int flat = blockIdx.x * 1024 + t * 256 + threadIdx.x;  // [0, 33792)
    int k2 = flat % SW_;
    float w = (k2 == 0 || k2 >= 128) ? 1.0f : 2.0f;
    float2 a0 = __half22float2(af[ab + flat]);
    float2 a1 = __half22float2(af[ab + SIMG_ + flat]);
    float2 a2 = __half22float2(af[ab + 2 * SIMG_ + flat]);
    float2 p0 = __half22float2(pf[ab + flat]);
    float2 p1 = __half22float2(pf[ab + SIMG_ + flat]);
    float2 p2 = __half22float2(pf[ab + 2 * SIMG_ + flat]);
    float2 n0 = __half22float2(nf[ab + flat]);
    float2 n1 = __half22float2(nf[ab + SIMG_ + flat]);
    float2 n2 = __half22float2(nf[ab + 2 * SIMG_ + flat]);
    float2 m0 = __half22float2(nf[jb + flat]);
    float2 m1 = __half22float2(nf[jb + SIMG_ + flat]);
    float2 m2 = __half22float2(nf[jb + 2 * SIMG_ + flat]);
    float sa = 0.01f / (sqrtf(cab2(a0) + cab2(a1) + cab2(a2)) + 1e-8f);
    float sp = 0.01f / (sqrtf(cab2(p0) + cab2(p1) + cab2(p2)) + 1e-8f);
    float sn = 0.01f / (sqrtf(cab2(n0) + cab2(n1) + cab2(n2)) + 1e-8f);
    float sm = 0.01f / (sqrtf(cab2(m0) + cab2(m1) + cab2(m2)) + 1e-8f);
    float dx, dy;
    dx = a0.x * sa - p0.x * sp; dy = a0.y * sa - p0.y * sp; s_ap += w * sqrtf(dx * dx + dy * dy);
    dx = a1.x * sa - p1.x * sp; dy = a1.y * sa - p1.y * sp; s_ap += w * sqrtf(dx * dx + dy * dy);
    dx = a2.x * sa - p2.x * sp; dy = a2.y * sa - p2.y * sp; s_ap += w * sqrtf(dx * dx + dy * dy);
    dx = a0.x * sa - n0.x * sn; dy = a0.y * sa - n0.y * sn; s_a0 += w * sqrtf(dx * dx + dy * dy);
    dx = a1.x * sa - n1.x * sn; dy = a1.y * sa - n1.y * sn; s_a0 += w * sqrtf(dx * dx + dy * dy);
    dx = a2.x * sa - n2.x * sn; dy = a2.y * sa - n2.y * sn; s_a0 += w * sqrtf(dx * dx + dy * dy);
    dx = a0.x * sa - m0.x * sm; dy = a0.y * sa - m0.y * sm; s_a1 += w * sqrtf(dx * dx + dy * dy);
    dx = a1.x * sa - m1.x * sm; dy = a1.y * sa - m1.y * sm; s_a1 += w * sqrtf(dx * dx + dy * dy);
    dx = a2.x * sa - m2.x * sm; dy = a2.y * sa - m2.y * sm; s_a1 += w * sqrtf(dx * dx + dy * dy);
  }
  // wave reduce (64 lanes)
#pragma unroll
  for (int off = 32; off > 0; off >>= 1) {
    s_ap += __shfl_down(s_ap, off);
    s_a0 += __shfl_down(s_a0, off);
    s_a1 += __shfl_down(s_a1, off);
  }
  __shared__ float red[3][4];
  int lane = threadIdx.x & 63, wid = threadIdx.x >> 6;
  if (lane == 0) { red[0][wid] = s_ap; red[1][wid] = s_a0; red[2][wid] = s_a1; }
  __syncthreads();
  if (threadIdx.x == 0) {
    atomicAdd(&acc[b * 3 + 0], red[0][0] + red[0][1] + red[0][2] + red[0][3]);
    atomicAdd(&acc[b * 3 + 1], red[1][0] + red[1][1] + red[1][2] + red[1][3]);
    atomicAdd(&acc[b * 3 + 2], red[2][0] + red[2][1] + red[2][2] + red[2][3]);
  }
}

__global__ void zero_acc(float* acc) { acc[threadIdx.x] = 0.0f; }

__global__ void final_kernel(const float* __restrict__ acc, float* __restrict__ out) {
  int b = threadIdx.x;  // 64 threads
  const float inv = 1.0f / 196608.0f;  // C*H*W (full grid)
  float dap = acc[b * 3 + 0] * inv;
  float da0 = acc[b * 3 + 1] * inv;
  float da1 = acc[b * 3 + 2] * inv;
  float term = dap / (da0 + 1e-7f) + dap / (da1 + 1e-7f);
#pragma unroll
  for (int off = 32; off > 0; off >>= 1) term += __shfl_down(term, off);
  if (b == 0) out[0] = term * (1.0f / 128.0f);  // / (K*B)
}

extern "C" void kernel_launch(void* const* d_in, const int* in_sizes, int n_in,
                              void* d_out, int out_size, void* d_ws, size_t ws_size,
                              hipStream_t stream) {
  const float* a = (const float*)d_in[0];
  const float* p = (const float*)d_in[1];
  const float* n = (const float*)d_in[2];
  const int* neg = (const int*)d_in[3];
  float* out = (float*)d_out;

  __half2* afh = (__half2*)d_ws;
  __half2* pfh = afh + TELEMS_;
  __half2* nfh = pfh + TELEMS_;
  float* acc = (float*)(nfh + TELEMS_);
  // total ws use: 3 * 6488064 * 4 B + 768 B ~= 74.3 MB

  zero_acc<<<1, 192, 0, stream>>>(acc);

  int rowBlocks = NROWS_ / 4;  // 12288
  fft_rows<<<rowBlocks, 256, 0, stream>>>(a, afh);
  fft_rows<<<rowBlocks, 256, 0, stream>>>(p, pfh);
  fft_rows<<<rowBlocks, 256, 0, stream>>>(n, nfh);

  dim3 colGrid(33, NCH_);  // 33 column groups x 192 images
  fft_cols<<<colGrid, 256, 0, stream>>>(afh);
  fft_cols<<<colGrid, 256, 0, stream>>>(pfh);
  fft_cols<<<colGrid, 256, 0, stream>>>(nfh);

  dist_kernel<<<dim3(33, 64), 256, 0, stream>>>(afh, pfh, nfh, neg, acc);
  final_kernel<<<1, 64, 0, stream>>>(acc, out);
}

// Round 3
// 378.623 us; speedup vs baseline: 1.1463x; 1.1463x over previous
//
#include <hip/hip_runtime.h>
#include <hip/hip_fp16.h>

// Problem constants
#define B_ 64
#define SW_ 132                 // stored k2 count: [0,128] real + [129,131] zero pad
#define SIMG_ (256 * SW_)       // 33792 half2 per channel plane (layout [k2][k1])
#define TIMG_ (3 * SIMG_)       // per batch item per tensor
#define TELEMS_ ((size_t)B_ * TIMG_)  // 6488064 half2 per tensor
#define LST_ 257                // LDS row stride (half2 elems) for S[k2][k1]

__device__ __forceinline__ float2 h2f(__half2 v) { return __half22float2(v); }
__device__ __forceinline__ __half2 f2h(float2 v) { return __float22half2_rn(v); }

// 256-pt radix-2 Stockham FFT, fp16 storage / fp32 arithmetic, twiddle LUT.
// One 64-lane wave per transform; 8 stages; result ends in the buffer passed
// as buf0. __syncthreads after every stage (all waves call this together).
__device__ __forceinline__ void fft_stages(__half2* buf0, __half2* buf1,
                                           const float2* tw, int r) {
  __half2* sp = buf0;
  __half2* dp = buf1;
#pragma unroll
  for (int s = 0; s < 8; ++s) {
    int m = 1 << s;
#pragma unroll
    for (int t = 0; t < 2; ++t) {
      int idx = r + t * 64;
      int k = idx & ~(m - 1);       // = (idx>>s)<<s, twiddle index in [0,128)
      float2 c0 = h2f(sp[idx]);
      float2 c1 = h2f(sp[idx + 128]);
      float2 w = tw[k];
      float2 d0 = make_float2(c0.x + c1.x, c0.y + c1.y);
      float ex = c0.x - c1.x, ey = c0.y - c1.y;
      float2 d1 = make_float2(ex * w.x - ey * w.y, ex * w.y + ey * w.x);
      int dst = idx + k;            // = idx + j*m
      dp[dst] = f2h(d0);
      dp[dst + m] = f2h(d1);
    }
    __half2* tmp = sp; sp = dp; dp = tmp;
    __syncthreads();
  }
}

// Fused 2D FFT per channel plane. Grid: 576 blocks (3 tensors x 192 planes),
// 512 threads (8 waves). Spectrum kept in LDS between row and column passes.
__global__ __launch_bounds__(512) void fft2_fused(const float* __restrict__ a,
                                                  const float* __restrict__ p,
                                                  const float* __restrict__ n,
                                                  __half2* __restrict__ outbase) {
  __shared__ __half2 S[SW_ * LST_];   // [k2][k1], stride 257: 135696 B
  __shared__ __half2 scr[8][512];     // per-wave ping-pong scratch: 16384 B
  __shared__ float2 TW[128];          // twiddles exp(-2*pi*i*k/256): 1024 B

  int tid = threadIdx.x;
  int wv = tid >> 6;
  int r = tid & 63;
  int tensor = blockIdx.x / 192;
  int plane = blockIdx.x % 192;        // = b*3 + c
  const float* in = (tensor == 0 ? a : (tensor == 1 ? p : n)) + (size_t)plane * 65536;
  __half2* out = outbase + (size_t)tensor * TELEMS_ + (size_t)plane * SIMG_;

  if (tid < 128) {
    float ang = -6.283185307179586f * (float)tid / 256.0f;
    float sw, cw;
    __sincosf(ang, &sw, &cw);
    TW[tid] = make_float2(cw, sw);
  }
  __syncthreads();

  // ---- Row pass: 128 packed-real FFTs (rows 2q, 2q+1 as one complex FFT) --
  for (int it = 0; it < 16; ++it) {     // 128 pairs / 8 waves = 16, uniform
    int q = it * 8 + wv;
    const float* r0 = in + (size_t)(2 * q) * 256;
    const float* r1 = r0 + 256;
    __half2* sp = scr[wv];
    __half2* dp = scr[wv] + 256;
#pragma unroll
    for (int t = 0; t < 4; ++t) {
      int idx = r + t * 64;
      sp[idx] = f2h(make_float2(r0[idx], r1[idx]));  // same-lane RAW only
    }
    fft_stages(sp, dp, TW, r);          // result in sp
    // Hermitian unpack: F0[k]=(Z[k]+conj(Z[-k]))/2, F1[k]=(Z[k]-conj(Z[-k]))/2i
#pragma unroll
    for (int t = 0; t < 2; ++t) {
      int k = r + t * 64;               // covers [0,128)
      float2 Zk = h2f(sp[k]);
      float2 Zm = h2f(sp[(256 - k) & 255]);
      float2 A = make_float2(0.5f * (Zk.x + Zm.x), 0.5f * (Zk.y - Zm.y));
      float2 Bv = make_float2(0.5f * (Zk.y + Zm.y), 0.5f * (Zm.x - Zk.x));
      S[k * LST_ + 2 * q] = f2h(A);
      S[k * LST_ + 2 * q + 1] = f2h(Bv);
    }
    if (r == 0) {                       // Nyquist column k2 = 128
      float2 Z = h2f(sp[128]);
      S[128 * LST_ + 2 * q] = f2h(make_float2(Z.x, 0.0f));
      S[128 * LST_ + 2 * q + 1] = f2h(make_float2(Z.y, 0.0f));
    }
    __syncthreads();                    // scratch reuse + S visibility
  }

  // ---- Column pass: FFT over k1 for each kept k2 (129 real columns) ------
  for (int it = 0; it < 17; ++it) {     // ceil(129/8); uniform barriers
    int c = it * 8 + wv;
    int ce = (c < SW_) ? c : (SW_ - 1); // clamp; cols 129..131 are garbage,
                                        // discarded at writeback (zeros)
    fft_stages(&S[ce * LST_], scr[wv], TW, r);  // ends back in S[ce]
  }

  // ---- Writeback: S -> global, zeros for pad cols ------------------------
  __syncthreads();
#pragma unroll
  for (int i = 0; i < 66; ++i) {        // 33792 / 512
    int e = i * 512 + tid;
    int k2 = e >> 8, k1 = e & 255;
    __half2 v = (k2 >= 129) ? f2h(make_float2(0.0f, 0.0f)) : S[k2 * LST_ + k1];
    out[e] = v;
  }
}

__device__ __forceinline__ float cab2(float2 v) { return v.x * v.x + v.y * v.y; }

// -------- Fused normalize + triplet distance accumulation ------------------
// Layout now [k2][k1]: flat = k2*256 + k1, Hermitian weight = f(k2) only.
__global__ __launch_bounds__(256) void dist_kernel(const __half2* __restrict__ af,
                                                   const __half2* __restrict__ pf,
                                                   const __half2* __restrict__ nf,
                                                   const int* __restrict__ neg,
                                                   float* __restrict__ acc) {
  int b = blockIdx.y;
  // neg_idx layout autodetect: int64 LE -> word[1] (hi half of elem 0) == 0.
  int j;
  if (neg[1] == 0) {
    j = (int)((const long long*)neg)[b * 2 + 1];
  } else {
    j = neg[b * 2 + 1];
  }
  size_t ab = (size_t)b * TIMG_;
  size_t jb = (size_t)j * TIMG_;
  float s_ap = 0.0f, s_a0 = 0.0f, s_a1 = 0.0f;
#pragma unroll
  for (int t = 0; t < 4; ++t) {
    int flat = blockIdx.x * 1024 + t * 256 + threadIdx.x;  // [0, 33792)
    int k2 = flat >> 8;
    float w = (k2 == 0 || k2 >= 128) ? 1.0f : 2.0f;  // pad cols are zero anyway
    float2 a0 = h2f(af[ab + flat]);
    float2 a1 = h2f(af[ab + SIMG_ + flat]);
    float2 a2 = h2f(af[ab + 2 * SIMG_ + flat]);
    float2 p0 = h2f(pf[ab + flat]);
    float2 p1 = h2f(pf[ab + SIMG_ + flat]);
    float2 p2 = h2f(pf[ab + 2 * SIMG_ + flat]);
    float2 n0 = h2f(nf[ab + flat]);
    float2 n1 = h2f(nf[ab + SIMG_ + flat]);
    float2 n2 = h2f(nf[ab + 2 * SIMG_ + flat]);
    float2 m0 = h2f(nf[jb + flat]);
    float2 m1 = h2f(nf[jb + SIMG_ + flat]);
    float2 m2 = h2f(nf[jb + 2 * SIMG_ + flat]);
    float sa = 0.01f / (sqrtf(cab2(a0) + cab2(a1) + cab2(a2)) + 1e-8f);
    float sp = 0.01f / (sqrtf(cab2(p0) + cab2(p1) + cab2(p2)) + 1e-8f);
    float sn = 0.01f / (sqrtf(cab2(n0) + cab2(n1) + cab2(n2)) + 1e-8f);
    float sm = 0.01f / (sqrtf(cab2(m0) + cab2(m1) + cab2(m2)) + 1e-8f);
    float dx, dy;
    dx = a0.x * sa - p0.x * sp; dy = a0.y * sa - p0.y * sp; s_ap += w * sqrtf(dx * dx + dy * dy);
    dx = a1.x * sa - p1.x * sp; dy = a1.y * sa - p1.y * sp; s_ap += w * sqrtf(dx * dx + dy * dy);
    dx = a2.x * sa - p2.x * sp; dy = a2.y * sa - p2.y * sp; s_ap += w * sqrtf(dx * dx + dy * dy);
    dx = a0.x * sa - n0.x * sn; dy = a0.y * sa - n0.y * sn; s_a0 += w * sqrtf(dx * dx + dy * dy);
    dx = a1.x * sa - n1.x * sn; dy = a1.y * sa - n1.y * sn; s_a0 += w * sqrtf(dx * dx + dy * dy);
    dx = a2.x * sa - n2.x * sn; dy = a2.y * sa - n2.y * sn; s_a0 += w * sqrtf(dx * dx + dy * dy);
    dx = a0.x * sa - m0.x * sm; dy = a0.y * sa - m0.y * sm; s_a1 += w * sqrtf(dx * dx + dy * dy);
    dx = a1.x * sa - m1.x * sm; dy = a1.y * sa - m1.y * sm; s_a1 += w * sqrtf(dx * dx + dy * dy);
    dx = a2.x * sa - m2.x * sm; dy = a2.y * sa - m2.y * sm; s_a1 += w * sqrtf(dx * dx + dy * dy);
  }
#pragma unroll
  for (int off = 32; off > 0; off >>= 1) {
    s_ap += __shfl_down(s_ap, off);
    s_a0 += __shfl_down(s_a0, off);
    s_a1 += __shfl_down(s_a1, off);
  }
  __shared__ float red[3][4];
  int lane = threadIdx.x & 63, wid = threadIdx.x >> 6;
  if (lane == 0) { red[0][wid] = s_ap; red[1][wid] = s_a0; red[2][wid] = s_a1; }
  __syncthreads();
  if (threadIdx.x == 0) {
    atomicAdd(&acc[b * 3 + 0], red[0][0] + red[0][1] + red[0][2] + red[0][3]);
    atomicAdd(&acc[b * 3 + 1], red[1][0] + red[1][1] + red[1][2] + red[1][3]);
    atomicAdd(&acc[b * 3 + 2], red[2][0] + red[2][1] + red[2][2] + red[2][3]);
  }
}

__global__ void zero_acc(float* acc) { acc[threadIdx.x] = 0.0f; }

__global__ void final_kernel(const float* __restrict__ acc, float* __restrict__ out) {
  int b = threadIdx.x;  // 64 threads
  const float inv = 1.0f / 196608.0f;  // C*H*W (full grid)
  float dap = acc[b * 3 + 0] * inv;
  float da0 = acc[b * 3 + 1] * inv;
  float da1 = acc[b * 3 + 2] * inv;
  float term = dap / (da0 + 1e-7f) + dap / (da1 + 1e-7f);
#pragma unroll
  for (int off = 32; off > 0; off >>= 1) term += __shfl_down(term, off);
  if (b == 0) out[0] = term * (1.0f / 128.0f);  // / (K*B)
}

extern "C" void kernel_launch(void* const* d_in, const int* in_sizes, int n_in,
                              void* d_out, int out_size, void* d_ws, size_t ws_size,
                              hipStream_t stream) {
  const float* a = (const float*)d_in[0];
  const float* p = (const float*)d_in[1];
  const float* n = (const float*)d_in[2];
  const int* neg = (const int*)d_in[3];
  float* out = (float*)d_out;

  __half2* base = (__half2*)d_ws;               // af | pf | nf, TELEMS_ each
  float* acc = (float*)(base + 3 * TELEMS_);    // ~74.3 MB + 768 B total

  zero_acc<<<1, 192, 0, stream>>>(acc);
  fft2_fused<<<576, 512, 0, stream>>>(a, p, n, base);
  dist_kernel<<<dim3(33, 64), 256, 0, stream>>>(base, base + TELEMS_,
                                                base + 2 * TELEMS_, neg, acc);
  final_kernel<<<1, 64, 0, stream>>>(acc, out);
}

// Round 4
// 253.458 us; speedup vs baseline: 1.7124x; 1.4938x over previous
//
#include <hip/hip_runtime.h>
#include <hip/hip_fp16.h>

// Problem constants
#define B_ 64
#define SW_ 132                 // stored k2 rows: [0,128] real + [129,131] zero pad
#define SIMG_ (256 * SW_)       // 33792 half2 per channel plane, layout [k2][k1perm]
#define TIMG_ (3 * SIMG_)       // per batch item per tensor
#define TELEMS_ ((size_t)B_ * TIMG_)  // 6488064 half2 per tensor
#define SST_ 257                // S row stride in half2 (odd -> bank spread)

__device__ __forceinline__ float2 h2f(__half2 v) { return __half22float2(v); }
__device__ __forceinline__ __half2 f2h(float2 v) { return __float22half2_rn(v); }
__device__ __forceinline__ float2 cmul(float2 a, float2 b) {
  return make_float2(a.x * b.x - a.y * b.y, a.x * b.y + a.y * b.x);
}
// XOR bank swizzle on logical element index (keeps 4-elem blocks intact)
__device__ __forceinline__ int PHI(int e) { return e ^ ((e >> 4) & 0x0C); }
// reverse 4 base-4 digits of an 8-bit index
__device__ __forceinline__ int REV4(int k) {
  return ((k & 3) << 6) | ((k & 0xC) << 2) | ((k >> 2) & 0xC) | ((k >> 6) & 3);
}
#define LGKM0 asm volatile("s_waitcnt lgkmcnt(0)" ::: "memory")

// One radix-4 DIF butterfly, in place, phi-swizzled addresses.
__device__ __forceinline__ void r4stage(__half2* w, int i0, int q,
                                        float2 ta, float2 tb, float2 tc, bool tw) {
  int p0 = PHI(i0), p1 = PHI(i0 + q), p2 = PHI(i0 + 2 * q), p3 = PHI(i0 + 3 * q);
  float2 x0 = h2f(w[p0]), x1 = h2f(w[p1]), x2 = h2f(w[p2]), x3 = h2f(w[p3]);
  float2 a = make_float2(x0.x + x2.x, x0.y + x2.y);
  float2 b = make_float2(x0.x - x2.x, x0.y - x2.y);
  float2 c = make_float2(x1.x + x3.x, x1.y + x3.y);
  float2 d = make_float2(x1.x - x3.x, x1.y - x3.y);
  float2 y0 = make_float2(a.x + c.x, a.y + c.y);
  float2 y1 = make_float2(b.x + d.y, b.y - d.x);   // (b - i d)
  float2 y2 = make_float2(a.x - c.x, a.y - c.y);
  float2 y3 = make_float2(b.x - d.y, b.y + d.x);   // (b + i d)
  if (tw) { y1 = cmul(y1, ta); y2 = cmul(y2, tb); y3 = cmul(y3, tc); }
  w[p0] = f2h(y0); w[p1] = f2h(y1); w[p2] = f2h(y2); w[p3] = f2h(y3);
}

// 256-pt radix-4 DIF, wave-private (no block barriers). Output at logical
// position i is X[REV4(i)]. tws: 9 per-lane register twiddles.
__device__ __forceinline__ void fft256_r4(__half2* w, int r, const float2* tws) {
  LGKM0;
  r4stage(w, r, 64, tws[0], tws[1], tws[2], true);
  LGKM0;
  r4stage(w, ((r >> 4) << 6) | (r & 15), 16, tws[3], tws[4], tws[5], true);
  LGKM0;
  r4stage(w, ((r >> 2) << 4) | (r & 3), 4, tws[6], tws[7], tws[8], true);
  LGKM0;
  float2 u = make_float2(1.0f, 0.0f);
  r4stage(w, 4 * r, 1, u, u, u, false);
  LGKM0;
}

// Fused 2D FFT per channel plane: 576 blocks x 1024 thr (16 waves).
// Row pass: packed-real pairs, wave-private scratch, no barriers.
// ONE __syncthreads. Column pass: in-place on exclusively-owned S rows.
__global__ __launch_bounds__(1024, 4) void fft2_fused(const float* __restrict__ a,
                                                      const float* __restrict__ p,
                                                      const float* __restrict__ n,
                                                      __half2* __restrict__ outbase) {
  __shared__ __half2 S[129 * SST_];    // 132612 B, [k2][phi(col)]
  __shared__ __half2 scr[16 * 256];    // 16384 B, per-wave FFT buffers

  int tid = threadIdx.x;
  int wv = tid >> 6;
  int r = tid & 63;
  int tensor = blockIdx.x / 192;
  int plane = blockIdx.x % 192;
  const float* in = (tensor == 0 ? a : (tensor == 1 ? p : n)) + (size_t)plane * 65536;
  __half2* outp = outbase + (size_t)tensor * TELEMS_ + (size_t)plane * SIMG_;

  // Per-lane register twiddles (constant across all FFTs of this kernel)
  float2 tw[9];
  {
    float s, c;
    __sincosf(-6.283185307179586f * (float)r / 256.0f, &s, &c);
    tw[0] = make_float2(c, s); tw[1] = cmul(tw[0], tw[0]); tw[2] = cmul(tw[1], tw[0]);
    __sincosf(-6.283185307179586f * (float)(r & 15) / 64.0f, &s, &c);
    tw[3] = make_float2(c, s); tw[4] = cmul(tw[3], tw[3]); tw[5] = cmul(tw[4], tw[3]);
    __sincosf(-6.283185307179586f * (float)(r & 3) / 16.0f, &s, &c);
    tw[6] = make_float2(c, s); tw[7] = cmul(tw[6], tw[6]); tw[8] = cmul(tw[7], tw[6]);
  }

  __half2* w = scr + wv * 256;

  // ---- Row pass: 128 packed-real FFTs (rows 2q,2q+1), 8 per wave ---------
  for (int it = 0; it < 8; ++it) {
    int q = it * 16 + wv;               // pair index [0,128)
    const float4* r0 = (const float4*)(in + (size_t)(2 * q) * 256);
    const float4* r1 = (const float4*)(in + (size_t)(2 * q + 1) * 256);
    float4 v0 = r0[r];
    float4 v1 = r1[r];
    int pb = PHI(4 * r);                // PHI preserves 4-blocks
    w[pb]     = f2h(make_float2(v0.x, v1.x));
    w[pb + 1] = f2h(make_float2(v0.y, v1.y));
    w[pb + 2] = f2h(make_float2(v0.z, v1.z));
    w[pb + 3] = f2h(make_float2(v0.w, v1.w));
    fft256_r4(w, r, tw);
    // Hermitian unpack: Z[k] at logical REV4(k)
#pragma unroll
    for (int t = 0; t < 2; ++t) {
      int k = r + 64 * t;               // [0,128)
      float2 Zk = h2f(w[PHI(REV4(k))]);
      float2 Zm = h2f(w[PHI(REV4((256 - k) & 255))]);
      float2 A  = make_float2(0.5f * (Zk.x + Zm.x), 0.5f * (Zk.y - Zm.y));
      float2 Bv = make_float2(0.5f * (Zk.y + Zm.y), 0.5f * (Zm.x - Zk.x));
      __half2* srow = S + k * SST_ + PHI(2 * q);
      srow[0] = f2h(A);
      srow[1] = f2h(Bv);
    }
    if (r == 0) {                       // Nyquist row k2=128
      float2 Z = h2f(w[PHI(REV4(128))]);
      __half2* srow = S + 128 * SST_ + PHI(2 * q);
      srow[0] = f2h(make_float2(Z.x, 0.0f));
      srow[1] = f2h(make_float2(Z.y, 0.0f));
    }
    LGKM0;                              // scr reused next iteration
  }

  __syncthreads();                      // the ONE block barrier

  // ---- Column pass: in-place FFT on S row c, direct global writeback -----
  for (int it = 0; it < 9; ++it) {
    int c = it * 16 + wv;
    if (c <= 128) {
      __half2* row = S + c * SST_;
      fft256_r4(row, r, tw);
      __half2* dst = outp + (size_t)c * 256;
#pragma unroll
      for (int t = 0; t < 4; ++t) {     // coalesced 256B stores
        int i = r + 64 * t;
        dst[i] = row[PHI(i)];
      }
    } else if (c < SW_) {               // zero pad rows 129..131
      __half2* dst = outp + (size_t)c * 256;
      __half2 z = f2h(make_float2(0.0f, 0.0f));
#pragma unroll
      for (int t = 0; t < 4; ++t) dst[r + 64 * t] = z;
    }
  }
}

__device__ __forceinline__ float cab2(float2 v) { return v.x * v.x + v.y * v.y; }

// -------- Fused normalize + triplet distance accumulation ------------------
// flat = k2*256 + k1perm; Hermitian weight depends only on k2 (natural).
__global__ __launch_bounds__(256) void dist_kernel(const __half2* __restrict__ af,
                                                   const __half2* __restrict__ pf,
                                                   const __half2* __restrict__ nf,
                                                   const int* __restrict__ neg,
                                                   float* __restrict__ acc) {
  int b = blockIdx.y;
  // neg_idx layout autodetect: int64 LE -> word[1] (hi half of elem 0) == 0.
  int j;
  if (neg[1] == 0) {
    j = (int)((const long long*)neg)[b * 2 + 1];
  } else {
    j = neg[b * 2 + 1];
  }
  size_t ab = (size_t)b * TIMG_;
  size_t jb = (size_t)j * TIMG_;
  float s_ap = 0.0f, s_a0 = 0.0f, s_a1 = 0.0f;
#pragma unroll
  for (int t = 0; t < 4; ++t) {
    int flat = blockIdx.x * 1024 + t * 256 + threadIdx.x;  // [0, 33792)
    int k2 = flat >> 8;
    float w = (k2 == 0 || k2 >= 128) ? 1.0f : 2.0f;  // pad rows are zero anyway
    float2 a0 = h2f(af[ab + flat]);
    float2 a1 = h2f(af[ab + SIMG_ + flat]);
    float2 a2 = h2f(af[ab + 2 * SIMG_ + flat]);
    float2 p0 = h2f(pf[ab + flat]);
    float2 p1 = h2f(pf[ab + SIMG_ + flat]);
    float2 p2 = h2f(pf[ab + 2 * SIMG_ + flat]);
    float2 n0 = h2f(nf[ab + flat]);
    float2 n1 = h2f(nf[ab + SIMG_ + flat]);
    float2 n2 = h2f(nf[ab + 2 * SIMG_ + flat]);
    float2 m0 = h2f(nf[jb + flat]);
    float2 m1 = h2f(nf[jb + SIMG_ + flat]);
    float2 m2 = h2f(nf[jb + 2 * SIMG_ + flat]);
    float sa = 0.01f / (sqrtf(cab2(a0) + cab2(a1) + cab2(a2)) + 1e-8f);
    float sp = 0.01f / (sqrtf(cab2(p0) + cab2(p1) + cab2(p2)) + 1e-8f);
    float sn = 0.01f / (sqrtf(cab2(n0) + cab2(n1) + cab2(n2)) + 1e-8f);
    float sm = 0.01f / (sqrtf(cab2(m0) + cab2(m1) + cab2(m2)) + 1e-8f);
    float dx, dy;
    dx = a0.x * sa - p0.x * sp; dy = a0.y * sa - p0.y * sp; s_ap += w * sqrtf(dx * dx + dy * dy);
    dx = a1.x * sa - p1.x * sp; dy = a1.y * sa - p1.y * sp; s_ap += w * sqrtf(dx * dx + dy * dy);
    dx = a2.x * sa - p2.x * sp; dy = a2.y * sa - p2.y * sp; s_ap += w * sqrtf(dx * dx + dy * dy);
    dx = a0.x * sa - n0.x * sn; dy = a0.y * sa - n0.y * sn; s_a0 += w * sqrtf(dx * dx + dy * dy);
    dx = a1.x * sa - n1.x * sn; dy = a1.y * sa - n1.y * sn; s_a0 += w * sqrtf(dx * dx + dy * dy);
    dx = a2.x * sa - n2.x * sn; dy = a2.y * sa - n2.y * sn; s_a0 += w * sqrtf(dx * dx + dy * dy);
    dx = a0.x * sa - m0.x * sm; dy = a0.y * sa - m0.y * sm; s_a1 += w * sqrtf(dx * dx + dy * dy);
    dx = a1.x * sa - m1.x * sm; dy = a1.y * sa - m1.y * sm; s_a1 += w * sqrtf(dx * dx + dy * dy);
    dx = a2.x * sa - m2.x * sm; dy = a2.y * sa - m2.y * sm; s_a1 += w * sqrtf(dx * dx + dy * dy);
  }
#pragma unroll
  for (int off = 32; off > 0; off >>= 1) {
    s_ap += __shfl_down(s_ap, off);
    s_a0 += __shfl_down(s_a0, off);
    s_a1 += __shfl_down(s_a1, off);
  }
  __shared__ float red[3][4];
  int lane = threadIdx.x & 63, wid = threadIdx.x >> 6;
  if (lane == 0) { red[0][wid] = s_ap; red[1][wid] = s_a0; red[2][wid] = s_a1; }
  __syncthreads();
  if (threadIdx.x == 0) {
    atomicAdd(&acc[b * 3 + 0], red[0][0] + red[0][1] + red[0][2] + red[0][3]);
    atomicAdd(&acc[b * 3 + 1], red[1][0] + red[1][1] + red[1][2] + red[1][3]);
    atomicAdd(&acc[b * 3 + 2], red[2][0] + red[2][1] + red[2][2] + red[2][3]);
  }
}

__global__ void zero_acc(float* acc) { acc[threadIdx.x] = 0.0f; }

__global__ void final_kernel(const float* __restrict__ acc, float* __restrict__ out) {
  int b = threadIdx.x;  // 64 threads
  const float inv = 1.0f / 196608.0f;  // C*H*W (full grid)
  float dap = acc[b * 3 + 0] * inv;
  float da0 = acc[b * 3 + 1] * inv;
  float da1 = acc[b * 3 + 2] * inv;
  float term = dap / (da0 + 1e-7f) + dap / (da1 + 1e-7f);
#pragma unroll
  for (int off = 32; off > 0; off >>= 1) term += __shfl_down(term, off);
  if (b == 0) out[0] = term * (1.0f / 128.0f);  // / (K*B)
}

extern "C" void kernel_launch(void* const* d_in, const int* in_sizes, int n_in,
                              void* d_out, int out_size, void* d_ws, size_t ws_size,
                              hipStream_t stream) {
  const float* a = (const float*)d_in[0];
  const float* p = (const float*)d_in[1];
  const float* n = (const float*)d_in[2];
  const int* neg = (const int*)d_in[3];
  float* out = (float*)d_out;

  __half2* base = (__half2*)d_ws;               // af | pf | nf, TELEMS_ each
  float* acc = (float*)(base + 3 * TELEMS_);    // ~74.3 MB + 768 B total

  zero_acc<<<1, 192, 0, stream>>>(acc);
  fft2_fused<<<576, 1024, 0, stream>>>(a, p, n, base);
  dist_kernel<<<dim3(33, 64), 256, 0, stream>>>(base, base + TELEMS_,
                                                base + 2 * TELEMS_, neg, acc);
  final_kernel<<<1, 64, 0, stream>>>(acc, out);
}

// Round 5
// 247.049 us; speedup vs baseline: 1.7569x; 1.0259x over previous
//
#include <hip/hip_runtime.h>
#include <hip/hip_fp16.h>

// Problem constants
#define B_ 64
#define SW_ 132                 // stored k2 rows: [0,128] real + [129,131] zero pad
#define SIMG_ (256 * SW_)       // 33792 packed half2 per channel plane
#define TIMG_ (3 * SIMG_)       // per batch item per tensor
#define TELEMS_ ((size_t)B_ * TIMG_)
#define SST_ 257                // S row stride (odd -> conflict-free strided access)

__device__ __forceinline__ float2 cmul(float2 a, float2 b) {
  return make_float2(a.x * b.x - a.y * b.y, a.x * b.y + a.y * b.x);
}
__device__ __forceinline__ unsigned f2u(float2 v) {
  __half2 h = __float22half2_rn(v);
  return __builtin_bit_cast(unsigned, h);
}
__device__ __forceinline__ float2 u2f(unsigned u) {
  return __half22float2(__builtin_bit_cast(__half2, u));
}

// radix-4 DIF butterfly on 4 slots (intra-lane), optional twiddles
__device__ __forceinline__ void bfly4(float2 x[4], float2 ta, float2 tb, float2 tc, bool tw) {
  float2 a = make_float2(x[0].x + x[2].x, x[0].y + x[2].y);
  float2 b = make_float2(x[0].x - x[2].x, x[0].y - x[2].y);
  float2 c = make_float2(x[1].x + x[3].x, x[1].y + x[3].y);
  float2 d = make_float2(x[1].x - x[3].x, x[1].y - x[3].y);
  float2 y1 = make_float2(b.x + d.y, b.y - d.x);   // b - i d
  float2 y2 = make_float2(a.x - c.x, a.y - c.y);
  float2 y3 = make_float2(b.x - d.y, b.y + d.x);   // b + i d
  x[0] = make_float2(a.x + c.x, a.y + c.y);
  if (tw) { y1 = cmul(y1, ta); y2 = cmul(y2, tb); y3 = cmul(y3, tc); }
  x[1] = y1; x[2] = y2; x[3] = y3;
}

// swap slot bit (pair A=bit0, B=bit1) with lane bit `bit`
__device__ __forceinline__ void xbit(unsigned& A, unsigned& B, int bit, int r) {
  bool hi = (r >> bit) & 1;
  int send = hi ? (int)A : (int)B;
  int got = __shfl_xor(send, 1 << bit, 64);
  if (hi) A = (unsigned)got; else B = (unsigned)got;
}
// swap slot DIGIT with lane digit at bits (bit+1, bit)
__device__ __forceinline__ void xdigit(unsigned u[4], int bit, int r) {
  xbit(u[0], u[1], bit, r);      // s0 <-> lane bit
  xbit(u[2], u[3], bit, r);
  xbit(u[0], u[2], bit + 1, r);  // s1 <-> lane bit+1
  xbit(u[1], u[3], bit + 1, r);
}

// Full 256-pt radix-4 DIF FFT, register-resident. Input x[4] fp32 with
// slot = d3 (element e = r + 64*slot). Output packed in u[4]:
// lane r slot s holds X[k], k = 64*s + 16*(r&3) + 4*((r>>2)&3) + (r>>4).
// fp16 rounding at each inter-stage exchange (same as R4's LDS version).
__device__ __forceinline__ void fft256_reg(float2 x[4], unsigned u[4], int r,
                                           const float2 tw[9]) {
  bfly4(x, tw[0], tw[1], tw[2], true);
#pragma unroll
  for (int s = 0; s < 4; ++s) u[s] = f2u(x[s]);
  xdigit(u, 4, r);                                  // d3 <-> d2
#pragma unroll
  for (int s = 0; s < 4; ++s) x[s] = u2f(u[s]);
  bfly4(x, tw[3], tw[4], tw[5], true);
#pragma unroll
  for (int s = 0; s < 4; ++s) u[s] = f2u(x[s]);
  xdigit(u, 2, r);                                  // d2 <-> d1
#pragma unroll
  for (int s = 0; s < 4; ++s) x[s] = u2f(u[s]);
  bfly4(x, tw[6], tw[7], tw[8], true);
#pragma unroll
  for (int s = 0; s < 4; ++s) u[s] = f2u(x[s]);
  xdigit(u, 0, r);                                  // d1 <-> d0
#pragma unroll
  for (int s = 0; s < 4; ++s) x[s] = u2f(u[s]);
  bfly4(x, tw[0], tw[0], tw[0], false);
#pragma unroll
  for (int s = 0; s < 4; ++s) u[s] = f2u(x[s]);
}

// Fused 2D FFT per channel plane: 576 blocks x 1024 thr (16 waves), one
// __syncthreads total. Row pass: packed-real pairs fully in registers;
// column pass: LDS row -> registers -> direct global writeback.
__global__ __launch_bounds__(1024, 4) void fft2_fused(const float* __restrict__ a,
                                                      const float* __restrict__ p,
                                                      const float* __restrict__ n,
                                                      unsigned* __restrict__ outbase) {
  __shared__ unsigned S[129 * SST_];   // 132612 B: [k2][col], packed half2

  int tid = threadIdx.x;
  int wv = tid >> 6;
  int r = tid & 63;
  int tensor = blockIdx.x / 192;
  int plane = blockIdx.x % 192;
  const float* in = (tensor == 0 ? a : (tensor == 1 ? p : n)) + (size_t)plane * 65536;
  unsigned* outp = outbase + (size_t)tensor * TELEMS_ + (size_t)plane * SIMG_;

  // Per-lane register twiddles (constant across all FFTs here)
  float2 tw[9];
  {
    float s, c;
    __sincosf(-6.283185307179586f * (float)r / 256.0f, &s, &c);
    tw[0] = make_float2(c, s); tw[1] = cmul(tw[0], tw[0]); tw[2] = cmul(tw[1], tw[0]);
    __sincosf(-6.283185307179586f * (float)(r & 15) / 64.0f, &s, &c);
    tw[3] = make_float2(c, s); tw[4] = cmul(tw[3], tw[3]); tw[5] = cmul(tw[4], tw[3]);
    __sincosf(-6.283185307179586f * (float)(r & 3) / 16.0f, &s, &c);
    tw[6] = make_float2(c, s); tw[7] = cmul(tw[6], tw[6]); tw[8] = cmul(tw[7], tw[6]);
  }
  // lane's low-6-bit frequency part m, and mirror source lane rp (all 4
  // mirror values of a lane live in the single lane rp)
  int m = ((r & 3) << 4) | (((r >> 2) & 3) << 2) | (r >> 4);
  int mp = (64 - m) & 63;
  int rp = ((mp >> 4) & 3) | (((mp >> 2) & 3) << 2) | ((mp & 3) << 4);

  // ---- Row pass: 128 packed-real FFTs (rows 2q,2q+1), 8 per wave ---------
  for (int it = 0; it < 8; ++it) {
    int q = it * 16 + wv;
    const float* r0 = in + (size_t)(2 * q) * 256;
    float2 x[4]; unsigned u[4];
#pragma unroll
    for (int j = 0; j < 4; ++j)
      x[j] = make_float2(r0[r + 64 * j], r0[256 + r + 64 * j]);
    fft256_reg(x, u, r, tw);
    unsigned mir[4];
#pragma unroll
    for (int t = 0; t < 4; ++t) mir[t] = (unsigned)__shfl((int)u[t], rp, 64);
    // Hermitian unpack; slots 0,1 give k = m, 64+m <= 127 (always valid)
#pragma unroll
    for (int s = 0; s < 2; ++s) {
      int k = 64 * s + m;
      int sp = (m == 0) ? ((4 - s) & 3) : (3 - s);
      float2 Zk = u2f(u[s]), Zm = u2f(mir[sp]);
      float2 A  = make_float2(0.5f * (Zk.x + Zm.x), 0.5f * (Zk.y - Zm.y));
      float2 Bv = make_float2(0.5f * (Zk.y + Zm.y), 0.5f * (Zm.x - Zk.x));
      S[k * SST_ + 2 * q]     = f2u(A);
      S[k * SST_ + 2 * q + 1] = f2u(Bv);
    }
    if (r == 0) {  // Nyquist row k2=128 (slot 2, self-mirror)
      float2 Zk = u2f(u[2]);
      S[128 * SST_ + 2 * q]     = f2u(make_float2(Zk.x, 0.0f));
      S[128 * SST_ + 2 * q + 1] = f2u(make_float2(Zk.y, 0.0f));
    }
  }

  __syncthreads();                      // the ONE block barrier

  // ---- Column pass: FFT S row c, write straight to global ----------------
  for (int it = 0; it < 9; ++it) {
    int c = it * 16 + wv;
    if (c <= 128) {
      unsigned* srow = S + c * SST_;
      float2 x[4]; unsigned u[4];
#pragma unroll
      for (int j = 0; j < 4; ++j) x[j] = u2f(srow[r + 64 * j]);  // slot = d3
      fft256_reg(x, u, r, tw);
      // physical pos 4r+s holds freq 64s+m -- fixed permutation, fine
      *(uint4*)(outp + (size_t)c * 256 + 4 * r) = make_uint4(u[0], u[1], u[2], u[3]);
    }
  }
  if (wv >= 13) {                       // zero pad rows 129..131
    int c = 129 + (wv - 13);
    *(uint4*)(outp + (size_t)c * 256 + 4 * r) = make_uint4(0, 0, 0, 0);
  }
}

__device__ __forceinline__ float cab2(float2 v) { return v.x * v.x + v.y * v.y; }

// -------- Fused normalize + triplet distance, uint4-vectorized -------------
__global__ __launch_bounds__(256) void dist_kernel(const unsigned* __restrict__ af,
                                                   const unsigned* __restrict__ pf,
                                                   const unsigned* __restrict__ nf,
                                                   const int* __restrict__ neg,
                                                   float* __restrict__ acc) {
  int b = blockIdx.y;
  int j = (neg[1] == 0) ? (int)((const long long*)neg)[b * 2 + 1] : neg[b * 2 + 1];
  size_t ab = (size_t)b * TIMG_;
  size_t jb = (size_t)j * TIMG_;
  int t4 = blockIdx.x * 256 + threadIdx.x;   // [0, 8448)
  int flat0 = t4 * 4;                        // 4 consecutive elems, same k2 row
  int k2 = flat0 >> 8;
  float w = (k2 == 0 || k2 >= 128) ? 1.0f : 2.0f;

  unsigned A[3][4], P[3][4], N[3][4], M[3][4];
#pragma unroll
  for (int ch = 0; ch < 3; ++ch) {
    uint4 t;
    t = *(const uint4*)(af + ab + ch * SIMG_ + flat0); A[ch][0]=t.x; A[ch][1]=t.y; A[ch][2]=t.z; A[ch][3]=t.w;
    t = *(const uint4*)(pf + ab + ch * SIMG_ + flat0); P[ch][0]=t.x; P[ch][1]=t.y; P[ch][2]=t.z; P[ch][3]=t.w;
    t = *(const uint4*)(nf + ab + ch * SIMG_ + flat0); N[ch][0]=t.x; N[ch][1]=t.y; N[ch][2]=t.z; N[ch][3]=t.w;
    t = *(const uint4*)(nf + jb + ch * SIMG_ + flat0); M[ch][0]=t.x; M[ch][1]=t.y; M[ch][2]=t.z; M[ch][3]=t.w;
  }
  float s_ap = 0.0f, s_a0 = 0.0f, s_a1 = 0.0f;
#pragma unroll
  for (int e = 0; e < 4; ++e) {
    float2 a0 = u2f(A[0][e]), a1 = u2f(A[1][e]), a2 = u2f(A[2][e]);
    float2 p0 = u2f(P[0][e]), p1 = u2f(P[1][e]), p2 = u2f(P[2][e]);
    float2 n0 = u2f(N[0][e]), n1 = u2f(N[1][e]), n2 = u2f(N[2][e]);
    float2 m0 = u2f(M[0][e]), m1 = u2f(M[1][e]), m2 = u2f(M[2][e]);
    float sa = 0.01f / (sqrtf(cab2(a0) + cab2(a1) + cab2(a2)) + 1e-8f);
    float sp = 0.01f / (sqrtf(cab2(p0) + cab2(p1) + cab2(p2)) + 1e-8f);
    float sn = 0.01f / (sqrtf(cab2(n0) + cab2(n1) + cab2(n2)) + 1e-8f);
    float sm = 0.01f / (sqrtf(cab2(m0) + cab2(m1) + cab2(m2)) + 1e-8f);
    float dx, dy;
    dx = a0.x * sa - p0.x * sp; dy = a0.y * sa - p0.y * sp; s_ap += sqrtf(dx * dx + dy * dy);
    dx = a1.x * sa - p1.x * sp; dy = a1.y * sa - p1.y * sp; s_ap += sqrtf(dx * dx + dy * dy);
    dx = a2.x * sa - p2.x * sp; dy = a2.y * sa - p2.y * sp; s_ap += sqrtf(dx * dx + dy * dy);
    dx = a0.x * sa - n0.x * sn; dy = a0.y * sa - n0.y * sn; s_a0 += sqrtf(dx * dx + dy * dy);
    dx = a1.x * sa - n1.x * sn; dy = a1.y * sa - n1.y * sn; s_a0 += sqrtf(dx * dx + dy * dy);
    dx = a2.x * sa - n2.x * sn; dy = a2.y * sa - n2.y * sn; s_a0 += sqrtf(dx * dx + dy * dy);
    dx = a0.x * sa - m0.x * sm; dy = a0.y * sa - m0.y * sm; s_a1 += sqrtf(dx * dx + dy * dy);
    dx = a1.x * sa - m1.x * sm; dy = a1.y * sa - m1.y * sm; s_a1 += sqrtf(dx * dx + dy * dy);
    dx = a2.x * sa - m2.x * sm; dy = a2.y * sa - m2.y * sm; s_a1 += sqrtf(dx * dx + dy * dy);
  }
  s_ap *= w; s_a0 *= w; s_a1 *= w;
#pragma unroll
  for (int off = 32; off > 0; off >>= 1) {
    s_ap += __shfl_down(s_ap, off);
    s_a0 += __shfl_down(s_a0, off);
    s_a1 += __shfl_down(s_a1, off);
  }
  __shared__ float red[3][4];
  int lane = threadIdx.x & 63, wid = threadIdx.x >> 6;
  if (lane == 0) { red[0][wid] = s_ap; red[1][wid] = s_a0; red[2][wid] = s_a1; }
  __syncthreads();
  if (threadIdx.x == 0) {
    atomicAdd(&acc[b * 3 + 0], red[0][0] + red[0][1] + red[0][2] + red[0][3]);
    atomicAdd(&acc[b * 3 + 1], red[1][0] + red[1][1] + red[1][2] + red[1][3]);
    atomicAdd(&acc[b * 3 + 2], red[2][0] + red[2][1] + red[2][2] + red[2][3]);
  }
}

__global__ void zero_acc(float* acc) { acc[threadIdx.x] = 0.0f; }

__global__ void final_kernel(const float* __restrict__ acc, float* __restrict__ out) {
  int b = threadIdx.x;  // 64 threads
  const float inv = 1.0f / 196608.0f;  // C*H*W (full grid)
  float dap = acc[b * 3 + 0] * inv;
  float da0 = acc[b * 3 + 1] * inv;
  float da1 = acc[b * 3 + 2] * inv;
  float term = dap / (da0 + 1e-7f) + dap / (da1 + 1e-7f);
#pragma unroll
  for (int off = 32; off > 0; off >>= 1) term += __shfl_down(term, off);
  if (b == 0) out[0] = term * (1.0f / 128.0f);  // / (K*B)
}

extern "C" void kernel_launch(void* const* d_in, const int* in_sizes, int n_in,
                              void* d_out, int out_size, void* d_ws, size_t ws_size,
                              hipStream_t stream) {
  const float* a = (const float*)d_in[0];
  const float* p = (const float*)d_in[1];
  const float* n = (const float*)d_in[2];
  const int* neg = (const int*)d_in[3];
  float* out = (float*)d_out;

  unsigned* base = (unsigned*)d_ws;             // af | pf | nf, TELEMS_ each
  float* acc = (float*)(base + 3 * TELEMS_);    // ~74.3 MB + 768 B total

  zero_acc<<<1, 192, 0, stream>>>(acc);
  fft2_fused<<<576, 1024, 0, stream>>>(a, p, n, base);
  dist_kernel<<<dim3(33, 64), 256, 0, stream>>>(base, base + TELEMS_,
                                                base + 2 * TELEMS_, neg, acc);
  final_kernel<<<1, 64, 0, stream>>>(acc, out);
}

// Round 6
// 245.706 us; speedup vs baseline: 1.7665x; 1.0055x over previous
//
#include <hip/hip_runtime.h>
#include <hip/hip_fp16.h>

// Problem constants
#define B_ 64
#define SW_ 132                 // stored k2 rows: [0,128] real + [129,131] zero pad
#define SIMG_ (256 * SW_)       // 33792 packed half2 per channel plane
#define TIMG_ (3 * SIMG_)       // per batch item per tensor
#define TELEMS_ ((size_t)B_ * TIMG_)
#define SST_ 257                // S row stride (odd -> conflict-free strided access)

__device__ __forceinline__ float2 cmul(float2 a, float2 b) {
  return make_float2(a.x * b.x - a.y * b.y, a.x * b.y + a.y * b.x);
}
__device__ __forceinline__ unsigned f2u(float2 v) {
  __half2 h = __float22half2_rn(v);
  return __builtin_bit_cast(unsigned, h);
}
__device__ __forceinline__ float2 u2f(unsigned u) {
  return __half22float2(__builtin_bit_cast(__half2, u));
}

// radix-4 DIF butterfly on 4 slots (intra-lane), optional twiddles
__device__ __forceinline__ void bfly4(float2 x[4], float2 ta, float2 tb, float2 tc, bool tw) {
  float2 a = make_float2(x[0].x + x[2].x, x[0].y + x[2].y);
  float2 b = make_float2(x[0].x - x[2].x, x[0].y - x[2].y);
  float2 c = make_float2(x[1].x + x[3].x, x[1].y + x[3].y);
  float2 d = make_float2(x[1].x - x[3].x, x[1].y - x[3].y);
  float2 y1 = make_float2(b.x + d.y, b.y - d.x);   // b - i d
  float2 y2 = make_float2(a.x - c.x, a.y - c.y);
  float2 y3 = make_float2(b.x - d.y, b.y + d.x);   // b + i d
  x[0] = make_float2(a.x + c.x, a.y + c.y);
  if (tw) { y1 = cmul(y1, ta); y2 = cmul(y2, tb); y3 = cmul(y3, tc); }
  x[1] = y1; x[2] = y2; x[3] = y3;
}

// swap slot bit (pair A=bit0, B=bit1) with lane bit `bit`
__device__ __forceinline__ void xbit(unsigned& A, unsigned& B, int bit, int r) {
  bool hi = (r >> bit) & 1;
  int send = hi ? (int)A : (int)B;
  int got = __shfl_xor(send, 1 << bit, 64);
  if (hi) A = (unsigned)got; else B = (unsigned)got;
}
// swap slot DIGIT with lane digit at bits (bit+1,bit) -- two FFTs interleaved
__device__ __forceinline__ void xdigit2(unsigned uA[4], unsigned uB[4], int bit, int r) {
  xbit(uA[0], uA[1], bit, r);
  xbit(uA[2], uA[3], bit, r);
  xbit(uB[0], uB[1], bit, r);
  xbit(uB[2], uB[3], bit, r);
  xbit(uA[0], uA[2], bit + 1, r);
  xbit(uA[1], uA[3], bit + 1, r);
  xbit(uB[0], uB[2], bit + 1, r);
  xbit(uB[1], uB[3], bit + 1, r);
}
__device__ __forceinline__ void xdigit(unsigned u[4], int bit, int r) {
  xbit(u[0], u[1], bit, r);
  xbit(u[2], u[3], bit, r);
  xbit(u[0], u[2], bit + 1, r);
  xbit(u[1], u[3], bit + 1, r);
}

// TWO independent 256-pt radix-4 DIF FFTs per wave, register-resident.
// Input x*[4] fp32 with slot = d3 (element e = r + 64*slot). Output packed:
// lane r slot s holds X[k], k = 64*s + 16*(r&3) + 4*((r>>2)&3) + (r>>4).
__device__ __forceinline__ void fft256_reg2(float2 xA[4], unsigned uA[4],
                                            float2 xB[4], unsigned uB[4],
                                            int r, const float2 tw[9]) {
  bfly4(xA, tw[0], tw[1], tw[2], true);
  bfly4(xB, tw[0], tw[1], tw[2], true);
#pragma unroll
  for (int s = 0; s < 4; ++s) { uA[s] = f2u(xA[s]); uB[s] = f2u(xB[s]); }
  xdigit2(uA, uB, 4, r);                            // d3 <-> d2
#pragma unroll
  for (int s = 0; s < 4; ++s) { xA[s] = u2f(uA[s]); xB[s] = u2f(uB[s]); }
  bfly4(xA, tw[3], tw[4], tw[5], true);
  bfly4(xB, tw[3], tw[4], tw[5], true);
#pragma unroll
  for (int s = 0; s < 4; ++s) { uA[s] = f2u(xA[s]); uB[s] = f2u(xB[s]); }
  xdigit2(uA, uB, 2, r);                            // d2 <-> d1
#pragma unroll
  for (int s = 0; s < 4; ++s) { xA[s] = u2f(uA[s]); xB[s] = u2f(uB[s]); }
  bfly4(xA, tw[6], tw[7], tw[8], true);
  bfly4(xB, tw[6], tw[7], tw[8], true);
#pragma unroll
  for (int s = 0; s < 4; ++s) { uA[s] = f2u(xA[s]); uB[s] = f2u(xB[s]); }
  xdigit2(uA, uB, 0, r);                            // d1 <-> d0
#pragma unroll
  for (int s = 0; s < 4; ++s) { xA[s] = u2f(uA[s]); xB[s] = u2f(uB[s]); }
  bfly4(xA, tw[0], tw[0], tw[0], false);
  bfly4(xB, tw[0], tw[0], tw[0], false);
#pragma unroll
  for (int s = 0; s < 4; ++s) { uA[s] = f2u(xA[s]); uB[s] = f2u(xB[s]); }
}

// single-FFT variant (Nyquist row only)
__device__ __forceinline__ void fft256_reg(float2 x[4], unsigned u[4], int r,
                                           const float2 tw[9]) {
  bfly4(x, tw[0], tw[1], tw[2], true);
#pragma unroll
  for (int s = 0; s < 4; ++s) u[s] = f2u(x[s]);
  xdigit(u, 4, r);
#pragma unroll
  for (int s = 0; s < 4; ++s) x[s] = u2f(u[s]);
  bfly4(x, tw[3], tw[4], tw[5], true);
#pragma unroll
  for (int s = 0; s < 4; ++s) u[s] = f2u(x[s]);
  xdigit(u, 2, r);
#pragma unroll
  for (int s = 0; s < 4; ++s) x[s] = u2f(u[s]);
  bfly4(x, tw[6], tw[7], tw[8], true);
#pragma unroll
  for (int s = 0; s < 4; ++s) u[s] = f2u(x[s]);
  xdigit(u, 0, r);
#pragma unroll
  for (int s = 0; s < 4; ++s) x[s] = u2f(u[s]);
  bfly4(x, tw[0], tw[0], tw[0], false);
#pragma unroll
  for (int s = 0; s < 4; ++s) u[s] = f2u(x[s]);
}

// Fused 2D FFT per channel plane: 576 blocks x 1024 thr (16 waves), one
// __syncthreads total, 2 FFTs in flight per wave (latency hiding).
__global__ __launch_bounds__(1024, 4) void fft2_fused(const float* __restrict__ a,
                                                      const float* __restrict__ p,
                                                      const float* __restrict__ n,
                                                      unsigned* __restrict__ outbase) {
  __shared__ unsigned S[129 * SST_];   // 132612 B: [k2][col], packed half2

  int tid = threadIdx.x;
  int wv = tid >> 6;
  int r = tid & 63;
  int tensor = blockIdx.x / 192;
  int plane = blockIdx.x % 192;
  const float* in = (tensor == 0 ? a : (tensor == 1 ? p : n)) + (size_t)plane * 65536;
  unsigned* outp = outbase + (size_t)tensor * TELEMS_ + (size_t)plane * SIMG_;

  // Per-lane register twiddles (constant across all FFTs here)
  float2 tw[9];
  {
    float s, c;
    __sincosf(-6.283185307179586f * (float)r / 256.0f, &s, &c);
    tw[0] = make_float2(c, s); tw[1] = cmul(tw[0], tw[0]); tw[2] = cmul(tw[1], tw[0]);
    __sincosf(-6.283185307179586f * (float)(r & 15) / 64.0f, &s, &c);
    tw[3] = make_float2(c, s); tw[4] = cmul(tw[3], tw[3]); tw[5] = cmul(tw[4], tw[3]);
    __sincosf(-6.283185307179586f * (float)(r & 3) / 16.0f, &s, &c);
    tw[6] = make_float2(c, s); tw[7] = cmul(tw[6], tw[6]); tw[8] = cmul(tw[7], tw[6]);
  }
  // lane's low-6-bit frequency part m; mirror source lane rp
  int m = ((r & 3) << 4) | (((r >> 2) & 3) << 2) | (r >> 4);
  int mp = (64 - m) & 63;
  int rp = ((mp >> 4) & 3) | (((mp >> 2) & 3) << 2) | ((mp & 3) << 4);

  // ---- Row pass: 128 packed-real FFTs (rows 2q,2q+1), 2 per wave per it --
  for (int it = 0; it < 4; ++it) {
    int qA = it * 16 + wv;              // [0,64)
    int qB = qA + 64;                   // [64,128)
    const float* rA = in + (size_t)(2 * qA) * 256;
    const float* rB = in + (size_t)(2 * qB) * 256;
    float2 xA[4], xB[4]; unsigned uA[4], uB[4];
#pragma unroll
    for (int j = 0; j < 4; ++j) {
      xA[j] = make_float2(rA[r + 64 * j], rA[256 + r + 64 * j]);
      xB[j] = make_float2(rB[r + 64 * j], rB[256 + r + 64 * j]);
    }
    fft256_reg2(xA, uA, xB, uB, r, tw);
    unsigned mirA[4], mirB[4];
#pragma unroll
    for (int t = 0; t < 4; ++t) {
      mirA[t] = (unsigned)__shfl((int)uA[t], rp, 64);
      mirB[t] = (unsigned)__shfl((int)uB[t], rp, 64);
    }
    // Hermitian unpack; slots 0,1 give k = m, 64+m <= 127 (always valid)
#pragma unroll
    for (int s = 0; s < 2; ++s) {
      int k = 64 * s + m;
      int sp = (m == 0) ? ((4 - s) & 3) : (3 - s);
      float2 ZkA = u2f(uA[s]), ZmA = u2f(mirA[sp]);
      float2 ZkB = u2f(uB[s]), ZmB = u2f(mirB[sp]);
      float2 Aa = make_float2(0.5f * (ZkA.x + ZmA.x), 0.5f * (ZkA.y - ZmA.y));
      float2 Ab = make_float2(0.5f * (ZkA.y + ZmA.y), 0.5f * (ZmA.x - ZkA.x));
      float2 Ba = make_float2(0.5f * (ZkB.x + ZmB.x), 0.5f * (ZkB.y - ZmB.y));
      float2 Bb = make_float2(0.5f * (ZkB.y + ZmB.y), 0.5f * (ZmB.x - ZkB.x));
      S[k * SST_ + 2 * qA]     = f2u(Aa);
      S[k * SST_ + 2 * qA + 1] = f2u(Ab);
      S[k * SST_ + 2 * qB]     = f2u(Ba);
      S[k * SST_ + 2 * qB + 1] = f2u(Bb);
    }
    if (r == 0) {  // Nyquist row k2=128 (slot 2, self-mirror)
      float2 ZA = u2f(uA[2]), ZB = u2f(uB[2]);
      S[128 * SST_ + 2 * qA]     = f2u(make_float2(ZA.x, 0.0f));
      S[128 * SST_ + 2 * qA + 1] = f2u(make_float2(ZA.y, 0.0f));
      S[128 * SST_ + 2 * qB]     = f2u(make_float2(ZB.x, 0.0f));
      S[128 * SST_ + 2 * qB + 1] = f2u(make_float2(ZB.y, 0.0f));
    }
  }

  __syncthreads();                      // the ONE block barrier

  // ---- Column pass: FFT S rows (2 per wave per it), direct global write --
  for (int it = 0; it < 4; ++it) {
    int cA = it * 16 + wv;              // [0,64)
    int cB = cA + 64;                   // [64,128)
    unsigned* rowA = S + cA * SST_;
    unsigned* rowB = S + cB * SST_;
    float2 xA[4], xB[4]; unsigned uA[4], uB[4];
#pragma unroll
    for (int j = 0; j < 4; ++j) {
      xA[j] = u2f(rowA[r + 64 * j]);    // slot = d3
      xB[j] = u2f(rowB[r + 64 * j]);
    }
    fft256_reg2(xA, uA, xB, uB, r, tw);
    // physical pos 4r+s holds freq 64s+m -- fixed within-row permutation, ok
    *(uint4*)(outp + (size_t)cA * 256 + 4 * r) = make_uint4(uA[0], uA[1], uA[2], uA[3]);
    *(uint4*)(outp + (size_t)cB * 256 + 4 * r) = make_uint4(uB[0], uB[1], uB[2], uB[3]);
  }
  if (wv == 0) {                        // row 128
    unsigned* srow = S + 128 * SST_;
    float2 x[4]; unsigned u[4];
#pragma unroll
    for (int j = 0; j < 4; ++j) x[j] = u2f(srow[r + 64 * j]);
    fft256_reg(x, u, r, tw);
    *(uint4*)(outp + (size_t)128 * 256 + 4 * r) = make_uint4(u[0], u[1], u[2], u[3]);
  }
  if (wv >= 13) {                       // zero pad rows 129..131
    int c = 129 + (wv - 13);
    *(uint4*)(outp + (size_t)c * 256 + 4 * r) = make_uint4(0, 0, 0, 0);
  }
}

__device__ __forceinline__ float cab2(float2 v) { return v.x * v.x + v.y * v.y; }

// -------- Fused normalize + triplet distance, uint4-vectorized -------------
__global__ __launch_bounds__(256) void dist_kernel(const unsigned* __restrict__ af,
                                                   const unsigned* __restrict__ pf,
                                                   const unsigned* __restrict__ nf,
                                                   const int* __restrict__ neg,
                                                   float* __restrict__ acc) {
  int b = blockIdx.y;
  int j = (neg[1] == 0) ? (int)((const long long*)neg)[b * 2 + 1] : neg[b * 2 + 1];
  size_t ab = (size_t)b * TIMG_;
  size_t jb = (size_t)j * TIMG_;
  int t4 = blockIdx.x * 256 + threadIdx.x;   // [0, 8448)
  int flat0 = t4 * 4;                        // 4 consecutive elems, same k2 row
  int k2 = flat0 >> 8;
  float w = (k2 == 0 || k2 >= 128) ? 1.0f : 2.0f;

  unsigned A[3][4], P[3][4], N[3][4], M[3][4];
#pragma unroll
  for (int ch = 0; ch < 3; ++ch) {
    uint4 t;
    t = *(const uint4*)(af + ab + ch * SIMG_ + flat0); A[ch][0]=t.x; A[ch][1]=t.y; A[ch][2]=t.z; A[ch][3]=t.w;
    t = *(const uint4*)(pf + ab + ch * SIMG_ + flat0); P[ch][0]=t.x; P[ch][1]=t.y; P[ch][2]=t.z; P[ch][3]=t.w;
    t = *(const uint4*)(nf + ab + ch * SIMG_ + flat0); N[ch][0]=t.x; N[ch][1]=t.y; N[ch][2]=t.z; N[ch][3]=t.w;
    t = *(const uint4*)(nf + jb + ch * SIMG_ + flat0); M[ch][0]=t.x; M[ch][1]=t.y; M[ch][2]=t.z; M[ch][3]=t.w;
  }
  float s_ap = 0.0f, s_a0 = 0.0f, s_a1 = 0.0f;
#pragma unroll
  for (int e = 0; e < 4; ++e) {
    float2 a0 = u2f(A[0][e]), a1 = u2f(A[1][e]), a2 = u2f(A[2][e]);
    float2 p0 = u2f(P[0][e]), p1 = u2f(P[1][e]), p2 = u2f(P[2][e]);
    float2 n0 = u2f(N[0][e]), n1 = u2f(N[1][e]), n2 = u2f(N[2][e]);
    float2 m0 = u2f(M[0][e]), m1 = u2f(M[1][e]), m2 = u2f(M[2][e]);
    float sa = 0.01f / (sqrtf(cab2(a0) + cab2(a1) + cab2(a2)) + 1e-8f);
    float sp = 0.01f / (sqrtf(cab2(p0) + cab2(p1) + cab2(p2)) + 1e-8f);
    float sn = 0.01f / (sqrtf(cab2(n0) + cab2(n1) + cab2(n2)) + 1e-8f);
    float sm = 0.01f / (sqrtf(cab2(m0) + cab2(m1) + cab2(m2)) + 1e-8f);
    float dx, dy;
    dx = a0.x * sa - p0.x * sp; dy = a0.y * sa - p0.y * sp; s_ap += sqrtf(dx * dx + dy * dy);
    dx = a1.x * sa - p1.x * sp; dy = a1.y * sa - p1.y * sp; s_ap += sqrtf(dx * dx + dy * dy);
    dx = a2.x * sa - p2.x * sp; dy = a2.y * sa - p2.y * sp; s_ap += sqrtf(dx * dx + dy * dy);
    dx = a0.x * sa - n0.x * sn; dy = a0.y * sa - n0.y * sn; s_a0 += sqrtf(dx * dx + dy * dy);
    dx = a1.x * sa - n1.x * sn; dy = a1.y * sa - n1.y * sn; s_a0 += sqrtf(dx * dx + dy * dy);
    dx = a2.x * sa - n2.x * sn; dy = a2.y * sa - n2.y * sn; s_a0 += sqrtf(dx * dx + dy * dy);
    dx = a0.x * sa - m0.x * sm; dy = a0.y * sa - m0.y * sm; s_a1 += sqrtf(dx * dx + dy * dy);
    dx = a1.x * sa - m1.x * sm; dy = a1.y * sa - m1.y * sm; s_a1 += sqrtf(dx * dx + dy * dy);
    dx = a2.x * sa - m2.x * sm; dy = a2.y * sa - m2.y * sm; s_a1 += sqrtf(dx * dx + dy * dy);
  }
  s_ap *= w; s_a0 *= w; s_a1 *= w;
#pragma unroll
  for (int off = 32; off > 0; off >>= 1) {
    s_ap += __shfl_down(s_ap, off);
    s_a0 += __shfl_down(s_a0, off);
    s_a1 += __shfl_down(s_a1, off);
  }
  __shared__ float red[3][4];
  int lane = threadIdx.x & 63, wid = threadIdx.x >> 6;
  if (lane == 0) { red[0][wid] = s_ap; red[1][wid] = s_a0; red[2][wid] = s_a1; }
  __syncthreads();
  if (threadIdx.x == 0) {
    atomicAdd(&acc[b * 3 + 0], red[0][0] + red[0][1] + red[0][2] + red[0][3]);
    atomicAdd(&acc[b * 3 + 1], red[1][0] + red[1][1] + red[1][2] + red[1][3]);
    atomicAdd(&acc[b * 3 + 2], red[2][0] + red[2][1] + red[2][2] + red[2][3]);
  }
}

__global__ void zero_acc(float* acc) { acc[threadIdx.x] = 0.0f; }

__global__ void final_kernel(const float* __restrict__ acc, float* __restrict__ out) {
  int b = threadIdx.x;  // 64 threads
  const float inv = 1.0f / 196608.0f;  // C*H*W (full grid)
  float dap = acc[b * 3 + 0] * inv;
  float da0 = acc[b * 3 + 1] * inv;
  float da1 = acc[b * 3 + 2] * inv;
  float term = dap / (da0 + 1e-7f) + dap / (da1 + 1e-7f);
#pragma unroll
  for (int off = 32; off > 0; off >>= 1) term += __shfl_down(term, off);
  if (b == 0) out[0] = term * (1.0f / 128.0f);  // / (K*B)
}

extern "C" void kernel_launch(void* const* d_in, const int* in_sizes, int n_in,
                              void* d_out, int out_size, void* d_ws, size_t ws_size,
                              hipStream_t stream) {
  const float* a = (const float*)d_in[0];
  const float* p = (const float*)d_in[1];
  const float* n = (const float*)d_in[2];
  const int* neg = (const int*)d_in[3];
  float* out = (float*)d_out;

  unsigned* base = (unsigned*)d_ws;             // af | pf | nf, TELEMS_ each
  float* acc = (float*)(base + 3 * TELEMS_);    // ~74.3 MB + 768 B total

  zero_acc<<<1, 192, 0, stream>>>(acc);
  fft2_fused<<<576, 1024, 0, stream>>>(a, p, n, base);
  dist_kernel<<<dim3(33, 64), 256, 0, stream>>>(base, base + TELEMS_,
                                                base + 2 * TELEMS_, neg, acc);
  final_kernel<<<1, 64, 0, stream>>>(acc, out);
}